// Round 10
// baseline (810.213 us; speedup 1.0000x reference)
//
#include <hip/hip_runtime.h>
#include <hip/hip_fp16.h>
#include <cstdint>
#include <cstddef>

// LSTM: B=32, T=1024, D=1024, H=128, gates 4H=512 (order i,f,g,o).
//   prep:     W_ih fp32->fp16, W_hh fp32->fp16, bsum = b_ih + b_hh
//   gemm_gx:  gx[32768][512] = x @ W_ih^T + bsum   (fp16 MFMA, fp32 acc)
//   lstm_rec: 32 blocks (1/batch) x 512 threads.
//   r9 lesson: recurrence was LDS-ISSUE-bound: 8 waves x 16 broadcast
//   ds_read_b128 = 128 LDS insts/CU-step x ~12cyc = ~1536cyc = measured wall.
//   r10 fix: thread t = (j = t>>2, s = t&3) where s is a K-SLICE: each lane
//   reads only h[32s..32s+32) (4 ds_read_b128/wave, 4x fewer), computes
//   32-length partials for ALL 4 gates of row j, quad-butterfly (8 DPP +
//   8 add) sums them; gx injected via 0/1 lane masks; c/h computed
//   redundantly by all 4 quad lanes (no divergent compute).

typedef __attribute__((ext_vector_type(8))) _Float16 half8;
typedef __attribute__((ext_vector_type(4))) _Float16 half4;
typedef __attribute__((ext_vector_type(4))) float    f32x4;

#define BT    32768   // B*T
#define DD    1024
#define GG    512     // 4*H
#define HH    128
#define TT    1024
#define BB    32

// ---------------- prep: fp16 conversions + bias sum ----------------
__global__ void prep_kernel(const float* __restrict__ wih,
                            const float* __restrict__ whh,
                            const float* __restrict__ bih,
                            const float* __restrict__ bhh,
                            _Float16* __restrict__ wih_h,
                            __half*   __restrict__ whh_h,
                            float* __restrict__ bsum) {
    int i = blockIdx.x * 256 + threadIdx.x;   // grid covers 512*1024 exactly
    wih_h[i] = (_Float16)wih[i];
    if (i < GG * HH) whh_h[i] = __float2half(whh[i]);
    if (i < GG)      bsum[i] = bih[i] + bhh[i];
}

// ---------------- GEMM: gx = x @ W_ih^T + bsum (unchanged, verified) --------
#define BM 128
#define BN 128
#define BK 32
#define LDP 40   // LDS row pitch in halves (80B rows, 2-way bank alias = free)

__global__ __launch_bounds__(256)
void gemm_gx(const float* __restrict__ x, const _Float16* __restrict__ wih_h,
             const float* __restrict__ bsum, float* __restrict__ gx) {
    const int bid = blockIdx.x;
    const int m0 = (bid >> 2) * BM;
    const int n0 = (bid & 3) * BN;
    const int t  = threadIdx.x;
    const int lane = t & 63;
    const int w  = t >> 6;
    const int wr = w >> 1, wc = w & 1;
    const int lr = lane & 15;
    const int lk = lane >> 4;

    __shared__ __align__(16) _Float16 As[BM][LDP];
    __shared__ __align__(16) _Float16 Bs[BN][LDP];

    f32x4 acc[4][4] = {};

    for (int kt = 0; kt < DD; kt += BK) {
        #pragma unroll
        for (int pass = 0; pass < 4; ++pass) {
            int r = pass * 32 + (t >> 3);
            int c = (t & 7) * 4;
            float4 v = *(const float4*)(x + (size_t)(m0 + r) * DD + kt + c);
            half4 hv;
            hv[0] = (_Float16)v.x; hv[1] = (_Float16)v.y;
            hv[2] = (_Float16)v.z; hv[3] = (_Float16)v.w;
            *(half4*)&As[r][c] = hv;
        }
        #pragma unroll
        for (int pass = 0; pass < 2; ++pass) {
            int r = pass * 64 + (t >> 2);
            int c = (t & 3) * 8;
            float4 v = *(const float4*)(wih_h + (size_t)(n0 + r) * DD + kt + c);
            *(float4*)&Bs[r][c] = v;
        }
        __syncthreads();

        half8 af[4], bf[4];
        #pragma unroll
        for (int i = 0; i < 4; ++i)
            af[i] = *(const half8*)&As[wr * 64 + i * 16 + lr][lk * 8];
        #pragma unroll
        for (int j = 0; j < 4; ++j)
            bf[j] = *(const half8*)&Bs[wc * 64 + j * 16 + lr][lk * 8];

        #pragma unroll
        for (int i = 0; i < 4; ++i)
            #pragma unroll
            for (int j = 0; j < 4; ++j)
                acc[i][j] = __builtin_amdgcn_mfma_f32_16x16x32_f16(af[i], bf[j], acc[i][j], 0, 0, 0);
        __syncthreads();
    }

    #pragma unroll
    for (int j = 0; j < 4; ++j) {
        int n = n0 + wc * 64 + j * 16 + lr;
        float bn = bsum[n];
        #pragma unroll
        for (int i = 0; i < 4; ++i) {
            int mbase = m0 + wr * 64 + i * 16 + lk * 4;
            #pragma unroll
            for (int r = 0; r < 4; ++r)
                gx[(size_t)(mbase + r) * GG + n] = acc[i][j][r] + bn;
        }
    }
}

// ---------------- recurrence ----------------
__device__ __forceinline__ __half2 u2h(uint32_t v) { return *(__half2*)&v; }

// DPP quad_perm lane swizzle (VALU; zero DS latency). ctrl must be immediate.
template <int CTRL>
__device__ __forceinline__ float dpp_qp(float x) {
    int i = __float_as_int(x);
    i = __builtin_amdgcn_update_dpp(0, i, CTRL, 0xF, 0xF, true);
    return __int_as_float(i);
}
#define QP_XOR1 0xB1   // [1,0,3,2]
#define QP_XOR2 0x4E   // [2,3,0,1]

#define LOG2E   1.4426950408889634f

// ---- 64 named weight dwords (4 gates x 16): no arrays, no dynamic index ----
#define WDECL(G,Q)  uint32_t w##G##Q##x, w##G##Q##y, w##G##Q##z, w##G##Q##w;
#define WLOAD(G,Q)  { uint4 u_ = wq[((G) * HH + j) * 16 + 4 * s_ + (Q)]; \
                      w##G##Q##x = u_.x; w##G##Q##y = u_.y; \
                      w##G##Q##z = u_.z; w##G##Q##w = u_.w; }
#define WPIN(G,Q)   asm volatile("" : "+v"(w##G##Q##x), "+v"(w##G##Q##y), \
                                      "+v"(w##G##Q##z), "+v"(w##G##Q##w));
#define WALL(F) F(0,0) F(0,1) F(0,2) F(0,3)  F(1,0) F(1,1) F(1,2) F(1,3) \
                F(2,0) F(2,1) F(2,2) F(2,3)  F(3,0) F(3,1) F(3,2) F(3,3)

// per-gate 32-MAC slice dot (2 chains of 8 pk_fma) + horizontal + gx inject
#define GATE_DOT(G) {                                          \
    __half2 cA_ = __float2half2_rn(0.f), cB_ = cA_;            \
    cA_ = __hfma2(u2h(w##G##0x), u2h(h0.x), cA_);              \
    cA_ = __hfma2(u2h(w##G##0y), u2h(h0.y), cA_);              \
    cA_ = __hfma2(u2h(w##G##0z), u2h(h0.z), cA_);              \
    cA_ = __hfma2(u2h(w##G##0w), u2h(h0.w), cA_);              \
    cA_ = __hfma2(u2h(w##G##1x), u2h(h1.x), cA_);              \
    cA_ = __hfma2(u2h(w##G##1y), u2h(h1.y), cA_);              \
    cA_ = __hfma2(u2h(w##G##1z), u2h(h1.z), cA_);              \
    cA_ = __hfma2(u2h(w##G##1w), u2h(h1.w), cA_);              \
    cB_ = __hfma2(u2h(w##G##2x), u2h(h2.x), cB_);              \
    cB_ = __hfma2(u2h(w##G##2y), u2h(h2.y), cB_);              \
    cB_ = __hfma2(u2h(w##G##2z), u2h(h2.z), cB_);              \
    cB_ = __hfma2(u2h(w##G##2w), u2h(h2.w), cB_);              \
    cB_ = __hfma2(u2h(w##G##3x), u2h(h3.x), cB_);              \
    cB_ = __hfma2(u2h(w##G##3y), u2h(h3.y), cB_);              \
    cB_ = __hfma2(u2h(w##G##3z), u2h(h3.z), cB_);              \
    cB_ = __hfma2(u2h(w##G##3w), u2h(h3.w), cB_);              \
    __half2 t_ = __hadd2(cA_, cB_);                            \
    P##G = fmaf(msk##G, p0, __low2float(t_) + __high2float(t_)); }

__global__ __launch_bounds__(512)
__attribute__((amdgpu_waves_per_eu(2, 2)))
void lstm_rec(const float* __restrict__ gx, const __half* __restrict__ whh_h,
              float* __restrict__ out, float* __restrict__ hn, float* __restrict__ cn) {
    const int b  = blockIdx.x;
    const int t  = threadIdx.x;
    const int j  = t >> 2;     // h-row
    const int s_ = t & 3;      // k-slice: h[32s..32s+32)

    __shared__ __align__(16) __half hbuf[2][HH];    // double-buffered h (512 B)
    __shared__ __align__(16) float  oring[64][HH];  // 64-step output ring (32 KiB)

    // weights: gate G, k-slice s_ -> 16 named uint4 (64 dwords), pinned
    const uint4* wq = (const uint4*)whh_h;
    WALL(WDECL)
    WALL(WLOAD)
    WALL(WPIN)

    // gx inject masks: this lane's gx element belongs to gate s_
    const float msk0 = (s_ == 0) ? 1.f : 0.f;
    const float msk1 = (s_ == 1) ? 1.f : 0.f;
    const float msk2 = (s_ == 2) ? 1.f : 0.f;
    const float msk3 = (s_ == 3) ? 1.f : 0.f;

    if (t < HH) hbuf[0][t] = __float2half(0.f);
    __syncthreads();

    const float* gxp  = gx + (size_t)b * TT * GG + (s_ * HH + j);
    float*       outp = out + (size_t)b * TT * HH;

    float c = 0.f, hval = 0.f;
    float p0 = gxp[0];
    float p1 = gxp[GG];

    for (int step = 0; step < TT; ++step) {
        // prefetch step+2 (register; distance 2 covers HBM/L2 latency)
        int sp = step + 2; if (sp > TT - 1) sp = TT - 1;
        float p2 = gxp[(size_t)sp * GG];

        // h slice: 4x ds_read_b128 (64 B), 2-way bank alias only (free)
        const uint4* hp = (const uint4*)((const char*)hbuf +
                                         ((step & 1) << 8) + (s_ << 6));
        uint4 h0 = hp[0], h1 = hp[1], h2 = hp[2], h3 = hp[3];

        // per-gate slice dots (64 pk_fma total) + gx inject
        float P0, P1, P2, P3;
        GATE_DOT(0) GATE_DOT(1) GATE_DOT(2) GATE_DOT(3)

        // quad butterfly: all 4 lanes end with full sums of all 4 gates
        P0 += dpp_qp<QP_XOR1>(P0);  P0 += dpp_qp<QP_XOR2>(P0);
        P1 += dpp_qp<QP_XOR1>(P1);  P1 += dpp_qp<QP_XOR2>(P1);
        P2 += dpp_qp<QP_XOR1>(P2);  P2 += dpp_qp<QP_XOR2>(P2);
        P3 += dpp_qp<QP_XOR1>(P3);  P3 += dpp_qp<QP_XOR2>(P3);

        // activations (i,f,o sigmoid; g tanh) — all lanes, no divergence
        float A0 = __builtin_amdgcn_rcpf(1.f + __builtin_amdgcn_exp2f(-LOG2E * P0));
        float A1 = __builtin_amdgcn_rcpf(1.f + __builtin_amdgcn_exp2f(-LOG2E * P1));
        float A2 = fmaf(2.f, __builtin_amdgcn_rcpf(
                        1.f + __builtin_amdgcn_exp2f(-2.f * LOG2E * P2)), -1.f);
        float A3 = __builtin_amdgcn_rcpf(1.f + __builtin_amdgcn_exp2f(-LOG2E * P3));

        // c/h update — redundant in all 4 quad lanes (identical values)
        c = fmaf(A1, c, A0 * A2);
        float th = fmaf(2.f, __builtin_amdgcn_rcpf(
                        1.f + __builtin_amdgcn_exp2f(-2.f * LOG2E * c)), -1.f);
        hval = A3 * th;

        if (s_ == 0) {
            hbuf[(step + 1) & 1][j] = __float2half(hval);
            oring[step & 63][j] = hval;       // out buffered in LDS, not global
        }

        // one barrier per step: LDS-only drain (no vmcnt on the serial chain)
        __builtin_amdgcn_sched_barrier(0);
        asm volatile("s_waitcnt lgkmcnt(0)" ::: "memory");
        __builtin_amdgcn_s_barrier();
        __builtin_amdgcn_sched_barrier(0);

        // coalesced flush of 64 steps of h (all 512 threads, float4)
        if ((step & 63) == 63) {
            float4*       dst = (float4*)(outp + (size_t)(step - 63) * HH);
            const float4* src = (const float4*)&oring[0][0];
            #pragma unroll
            for (int k = 0; k < 4; ++k)
                dst[t + k * 512] = src[t + k * 512];
            __syncthreads();   // ring-reuse guard (once per 64 steps)
        }

        p0 = p1; p1 = p2;
    }

    if (s_ == 0) {
        hn[b * HH + j] = hval;
        cn[b * HH + j] = c;
    }
}

// ---------------- launch ----------------
extern "C" void kernel_launch(void* const* d_in, const int* in_sizes, int n_in,
                              void* d_out, int out_size, void* d_ws, size_t ws_size,
                              hipStream_t stream) {
    const float* x   = (const float*)d_in[0];
    const float* wih = (const float*)d_in[1];
    const float* whh = (const float*)d_in[2];
    const float* bih = (const float*)d_in[3];
    const float* bhh = (const float*)d_in[4];
    float* out = (float*)d_out;

    // ws layout: [W_ih fp16 1MB][W_hh fp16 128KB][bsum 2KB pad->4KB][gx fp32 64MB]
    char* ws = (char*)d_ws;
    _Float16* wih_h = (_Float16*)ws;
    __half*   whh_h = (__half*)(ws + (size_t)(1 << 20));
    float*    bsum  = (float*)(ws + (size_t)(1 << 20) + (128 << 10));
    float*    gx    = (float*)(ws + (size_t)(1 << 20) + (128 << 10) + 4096);

    prep_kernel<<<(GG * DD) / 256, 256, 0, stream>>>(wih, whh, bih, bhh, wih_h, whh_h, bsum);
    gemm_gx<<<(BT / BM) * (GG / BN), 256, 0, stream>>>(x, wih_h, bsum, gx);

    float* hn = out + (size_t)BB * TT * HH;
    float* cn = hn + BB * HH;
    lstm_rec<<<BB, 512, 0, stream>>>(gx, whh_h, out, hn, cn);
}